// Round 5
// baseline (140.305 us; speedup 1.0000x reference)
//
#include <hip/hip_runtime.h>
#include <stdint.h>

#define N_PTS 131072
#define NCLS 8
#define MT 64      // points per tile
#define CAP 32768  // per-class capacity (~16.4k actual)
#define PS 2.8853900817779268f  // 2*log2(e) weight prescale

typedef __bf16 bf16x8 __attribute__((ext_vector_type(8)));
typedef float f32x4 __attribute__((ext_vector_type(4)));

__device__ __forceinline__ float exp2_fast(float a) {
#if __has_builtin(__builtin_amdgcn_exp2f)
  return __builtin_amdgcn_exp2f(a);
#else
  return exp2f(a);
#endif
}

// tanh(x) with a = PS*x: tanh = 1 - 2/(2^a + 1)
__device__ __forceinline__ float tanh_p2(float a) {
  return fmaf(-2.0f, __builtin_amdgcn_rcpf(exp2_fast(a) + 1.0f), 1.0f);
}

__device__ __forceinline__ unsigned short f2bf_rne(float f) {
  unsigned u = __float_as_uint(f);
  u = u + 0x7fffu + ((u >> 16) & 1u);
  return (unsigned short)(u >> 16);
}

// pack two floats to bf16 pair (round-half-up): {lo16: bf(a), hi16: bf(b)}
__device__ __forceinline__ unsigned pack_bf16(float a, float b) {
  unsigned ua = __float_as_uint(a) + 0x8000u;
  unsigned ub = __float_as_uint(b) + 0x8000u;
  return __builtin_amdgcn_perm(ub, ua, 0x07060302u);
}

// ---------------- fused prep kernel ----------------
// hdr ints [0..7] = per-class cursors (memset to 0 before launch).
// packed23: bf16 [l(2)][c][k/8][j][k%8] — A-frags, value = PS*W[k][j]
#define PK2_BLKS 512   // transpose-pack W2/W3: block = (cl, k8), thread = j
#define MISC_BLKS 177
#define MISC_N 45184
#define SCAT_BLKS 512
#define PREP_GRID (PK2_BLKS + MISC_BLKS + SCAT_BLKS)

__global__ __launch_bounds__(256) void k_prep(
    const int* __restrict__ times,
    const float* __restrict__ W1, const float* __restrict__ b1,
    const float* __restrict__ W2, const float* __restrict__ b2,
    const float* __restrict__ W3, const float* __restrict__ b3,
    const float* __restrict__ W4, const float* __restrict__ b4,
    int* __restrict__ hdr, int* __restrict__ sortedIdx,
    unsigned short* __restrict__ packed23,
    float* __restrict__ w1p, float* __restrict__ b2p,
    float* __restrict__ b3p, float* __restrict__ b4p,
    unsigned short* __restrict__ W4p) {
  __shared__ int lh[NCLS], lbase[NCLS];

  int b = blockIdx.x;
  int tid = threadIdx.x;

  if (b < PK2_BLKS) {
    // LDS-free transpose-pack: thread (k8, j) reads 8 coalesced floats,
    // writes one 16B frag. cl = class-layer, 32 k8-blocks per cl.
    int cl = b >> 5;               // 0..15
    int k8 = b & 31;
    int j = tid;
    int l = cl >> 3, c = cl & 7;
    const float* W = (l ? W3 : W2) + c * 65536 + k8 * 8 * 256 + j;
    float v0 = W[0],        v1 = W[256],     v2 = W[2 * 256], v3 = W[3 * 256];
    float v4 = W[4 * 256],  v5 = W[5 * 256], v6 = W[6 * 256], v7 = W[7 * 256];
    uint4 pk;
    pk.x = (unsigned)f2bf_rne(PS * v0) | ((unsigned)f2bf_rne(PS * v1) << 16);
    pk.y = (unsigned)f2bf_rne(PS * v2) | ((unsigned)f2bf_rne(PS * v3) << 16);
    pk.z = (unsigned)f2bf_rne(PS * v4) | ((unsigned)f2bf_rne(PS * v5) << 16);
    pk.w = (unsigned)f2bf_rne(PS * v6) | ((unsigned)f2bf_rne(PS * v7) << 16);
    *(uint4*)&packed23[cl * 65536 + (k8 * 256 + j) * 8] = pk;
  } else if (b < PK2_BLKS + MISC_BLKS) {
    int e2 = (b - PK2_BLKS) * 256 + tid;
    if (e2 < 8192) {          // w1p: [c][j][4] = PS*{w0,w1,w2,b}
      int c = e2 >> 10, rem = e2 & 1023;
      int j = rem >> 2, t = rem & 3;
      float v = (t < 3) ? W1[c * 768 + t * 256 + j] : b1[c * 256 + j];
      w1p[e2] = PS * v;
    } else if (e2 < 10240) {
      int i = e2 - 8192;
      b2p[i] = PS * b2[i];
    } else if (e2 < 12288) {
      int i = e2 - 10240;
      b3p[i] = PS * b3[i];
    } else if (e2 < 12416) {  // b4p: [c][16]
      int i = e2 - 12288;
      int c = i >> 4, r = i & 15;
      b4p[i] = (r < 3) ? PS * b4[c * 3 + r] : 0.0f;
    } else if (e2 < MISC_N) { // W4p: [c][k/8][j(16)][k%8]
      int i = e2 - 12416;
      int c = i >> 12, rem = i & 4095;
      int jj = rem & 7, j = (rem >> 3) & 15, k = ((rem >> 7) << 3) + jj;
      float v = (j < 3) ? PS * W4[c * 768 + k * 3 + j] : 0.0f;
      W4p[c * 4096 + rem] = f2bf_rne(v);
    }
  } else {
    int sb = b - (PK2_BLKS + MISC_BLKS);
    if (tid < NCLS) lh[tid] = 0;
    __syncthreads();
    int i = sb * 256 + tid;
    int t = times[i];
    int r = atomicAdd(&lh[t], 1);
    __syncthreads();
    if (tid < NCLS) lbase[tid] = lh[tid] ? atomicAdd(&hdr[tid], lh[tid]) : 0;
    __syncthreads();
    sortedIdx[t * CAP + lbase[t] + r] = i;
  }
}

// ---------------- main MLP kernel ----------------
// 512 thr = 8 waves; wave w owns j in [w*32, w*32+32).
// Abuf (B-frags): [k/8][m][k%8]. A=weights (REGISTER-RESIDENT), B=acts
// -> C[j][m]; lane holds 4 consecutive j at fixed m -> ds_write_b64 epilogue.
template <bool PRELOAD_NEXT>
__device__ __forceinline__ void mfma_layer16(
    unsigned short (*__restrict__ Abuf)[MT][8],
    bf16x8 (&af)[2][8],                 // this layer's weights (in regs)
    bf16x8 (&afn)[2][8],                // preload target for next layer
    const bf16x8* __restrict__ nextAf,  // next layer's frag array (global)
    const float* __restrict__ biasp,    // [256] prescaled
    int tid) {
  int lane = tid & 63, w = tid >> 6;
  int quad = lane >> 4, l16 = lane & 15;
  int jcol = w * 32 + l16;

  f32x4 acc[2][4];  // [jf][mt]
#pragma unroll
  for (int jf = 0; jf < 2; jf++) {
    f32x4 bv = *(const f32x4*)&biasp[w * 32 + jf * 16 + quad * 4];
#pragma unroll
    for (int mt = 0; mt < 4; mt++) acc[jf][mt] = bv;
  }

#pragma unroll
  for (int kb = 0; kb < 8; kb++) {
    int kq = kb * 4 + quad;
    bf16x8 bfr[4];
#pragma unroll
    for (int mt = 0; mt < 4; mt++)
      bfr[mt] = *(const bf16x8*)&Abuf[kq][mt * 16 + l16][0];
#pragma unroll
    for (int jf = 0; jf < 2; jf++)
#pragma unroll
      for (int mt = 0; mt < 4; mt++)
        acc[jf][mt] = __builtin_amdgcn_mfma_f32_16x16x32_bf16(af[jf][kb], bfr[mt], acc[jf][mt], 0, 0, 0);
  }

  __syncthreads();  // all Abuf reads done block-wide; safe to overwrite

  if (PRELOAD_NEXT) {
    // issue next layer's weight loads now: latency covered by epilogue+barrier
#pragma unroll
    for (int jf = 0; jf < 2; jf++)
#pragma unroll
      for (int kb = 0; kb < 8; kb++)
        afn[jf][kb] = nextAf[(kb * 4 + quad) * 256 + jcol + jf * 16];
  }

#pragma unroll
  for (int jf = 0; jf < 2; jf++) {
    int jbase = w * 32 + jf * 16 + quad * 4;  // 4 consecutive j per lane
#pragma unroll
    for (int mt = 0; mt < 4; mt++) {
      float t0 = tanh_p2(acc[jf][mt][0]);
      float t1 = tanh_p2(acc[jf][mt][1]);
      float t2 = tanh_p2(acc[jf][mt][2]);
      float t3 = tanh_p2(acc[jf][mt][3]);
      uint2 pk = make_uint2(pack_bf16(t0, t1), pack_bf16(t2, t3));
      *(uint2*)&Abuf[jbase >> 3][mt * 16 + l16][jbase & 7] = pk;
    }
  }
}

__global__ __launch_bounds__(512, 4) void k_mlp(
    const float* __restrict__ pos,
    const int* __restrict__ hdr, const int* __restrict__ sortedIdx,
    const unsigned short* __restrict__ packed23,
    const float* __restrict__ w1p, const float* __restrict__ b2p,
    const float* __restrict__ b3p, const float* __restrict__ b4p,
    const unsigned short* __restrict__ W4p,
    float* __restrict__ out) {

  __shared__ __align__(16) unsigned short Abuf[32][MT][8];  // 32 KB
  __shared__ __align__(16) float4 w1i[256];                 // 4 KB
  __shared__ __align__(16) float4 xpos4[MT];
  __shared__ int sIdx[MT];

  int b = blockIdx.x;
  int tid = threadIdx.x;

  // derive (class, tile) from per-class counts
  int c = -1, t0 = 0, cnt = 0;
  {
    int ts = 0;
#pragma unroll
    for (int cc = 0; cc < NCLS; cc++) {
      int cc_cnt = hdr[cc];
      int tiles = (cc_cnt + MT - 1) >> 6;
      if (b >= ts && b < ts + tiles) { c = cc; t0 = b - ts; cnt = cc_cnt; }
      ts += tiles;
    }
  }
  if (c < 0) return;
  int base = c * CAP + t0 * MT;
  int mCount = min(MT, cnt - t0 * MT);

  int lane = tid & 63, w = tid >> 6;
  int quad = lane >> 4, l16 = lane & 15;
  int jcol = w * 32 + l16;

  // preload layer-2 weight frags into registers (in flight during staging+L1)
  const bf16x8* Af2 = (const bf16x8*)(packed23 + ((size_t)c << 16));
  const bf16x8* Af3 = (const bf16x8*)(packed23 + ((size_t)(8 + c) << 16));
  bf16x8 afA[2][8], afB[2][8];
#pragma unroll
  for (int jf = 0; jf < 2; jf++)
#pragma unroll
    for (int kb = 0; kb < 8; kb++)
      afA[jf][kb] = Af2[(kb * 4 + quad) * 256 + jcol + jf * 16];

  if (tid < MT) sIdx[tid] = sortedIdx[base + min(tid, mCount - 1)];
  if (tid < 256) w1i[tid] = ((const float4*)(w1p + (size_t)c * 1024))[tid];
  __syncthreads();
  if (tid < MT) {
    int idx = sIdx[tid] * 3;
    xpos4[tid] = make_float4(pos[idx], pos[idx + 1], pos[idx + 2], 0.0f);
  }
  __syncthreads();

  // ---- layer 1 (fp32 VALU): each wave covers 32 j ----
  {
    int m = tid & 63, q = tid >> 6;   // q in 0..7
    float4 xp = xpos4[m];
#pragma unroll
    for (int i8 = 0; i8 < 4; i8++) {
      int j8 = q * 4 + i8;
      unsigned pk[4];
#pragma unroll
      for (int jp = 0; jp < 4; jp++) {
        float t[2];
#pragma unroll
        for (int u = 0; u < 2; u++) {
          float4 wv = w1i[j8 * 8 + jp * 2 + u];
          float a = fmaf(xp.x, wv.x, fmaf(xp.y, wv.y, fmaf(xp.z, wv.z, wv.w)));
          t[u] = tanh_p2(a);
        }
        pk[jp] = pack_bf16(t[0], t[1]);
      }
      *(uint4*)&Abuf[j8][m][0] = make_uint4(pk[0], pk[1], pk[2], pk[3]);
    }
  }
  __syncthreads();

  // ---- layers 2,3 (MFMA, weights in regs, in-place Abuf) ----
  mfma_layer16<true>(Abuf, afA, afB, Af3, b2p + c * 256, tid);
  __syncthreads();
  mfma_layer16<false>(Abuf, afB, afA, nullptr, b3p + c * 256, tid);
  __syncthreads();

  // ---- layer 4 (16x16x32 MFMA, j padded 3->16): waves 0..3 -> m-tiles ----
  if (w < 4) {
    f32x4 acc = *(const f32x4*)&b4p[c * 16 + quad * 4];
#pragma unroll
    for (int kb = 0; kb < 8; kb++) {
      int kq = kb * 4 + quad;
      bf16x8 a4 = *(const bf16x8*)&W4p[((size_t)c * 512 + kq * 16 + l16) * 8];
      bf16x8 b4f = *(const bf16x8*)&Abuf[kq][w * 16 + l16][0];
      acc = __builtin_amdgcn_mfma_f32_16x16x32_bf16(a4, b4f, acc, 0, 0, 0);
    }
    int m = w * 16 + l16;
    if (quad == 0 && m < mCount) {
      int o = sIdx[m] * 3;
      out[o + 0] = tanh_p2(acc[0]);
      out[o + 1] = tanh_p2(acc[1]);
      out[o + 2] = tanh_p2(acc[2]);
    }
  }
}

extern "C" void kernel_launch(void* const* d_in, const int* in_sizes, int n_in,
                              void* d_out, int out_size, void* d_ws, size_t ws_size,
                              hipStream_t stream) {
  const float* pos = (const float*)d_in[0];
  const int* times = (const int*)d_in[1];
  const float* W1 = (const float*)d_in[2];
  const float* b1 = (const float*)d_in[3];
  const float* W2 = (const float*)d_in[4];
  const float* b2 = (const float*)d_in[5];
  const float* W3 = (const float*)d_in[6];
  const float* b3 = (const float*)d_in[7];
  const float* W4 = (const float*)d_in[8];
  const float* b4 = (const float*)d_in[9];

  char* ws = (char*)d_ws;
  int* hdr = (int*)ws;
  int* sortedIdx = (int*)(ws + 4096);                    // 1 MB
  float* w1p = (float*)(ws + 1052672);                   // 32 KB
  float* b2p = (float*)(ws + 1085440);                   // 8 KB
  float* b3p = (float*)(ws + 1093632);                   // 8 KB
  float* b4p = (float*)(ws + 1101824);                   // 512 B
  unsigned short* W4p = (unsigned short*)(ws + 1102336); // 64 KB
  unsigned short* packed23 = (unsigned short*)(ws + (2u << 20)); // 2 MB
  float* out = (float*)d_out;

  hipMemsetAsync(d_ws, 0, 64, stream);
  k_prep<<<PREP_GRID, 256, 0, stream>>>(times, W1, b1, W2, b2, W3, b3, W4, b4,
                                        hdr, sortedIdx, packed23,
                                        w1p, b2p, b3p, b4p, W4p);
  k_mlp<<<N_PTS / MT + NCLS, 512, 0, stream>>>(
      pos, hdr, sortedIdx, packed23, w1p, b2p, b3p, b4p, W4p, out);
}

// Round 6
// 131.912 us; speedup vs baseline: 1.0636x; 1.0636x over previous
//
#include <hip/hip_runtime.h>
#include <stdint.h>

#define N_PTS 131072
#define NCLS 8
#define MT 64      // points per tile
#define CAP 32768  // per-class capacity (~16.4k actual)
#define PS 2.8853900817779268f  // 2*log2(e) weight prescale

typedef __bf16 bf16x8 __attribute__((ext_vector_type(8)));
typedef float f32x4 __attribute__((ext_vector_type(4)));

__device__ __forceinline__ float exp2_fast(float a) {
#if __has_builtin(__builtin_amdgcn_exp2f)
  return __builtin_amdgcn_exp2f(a);
#else
  return exp2f(a);
#endif
}

// tanh(x) with a = PS*x: tanh = 1 - 2/(2^a + 1)
__device__ __forceinline__ float tanh_p2(float a) {
  return fmaf(-2.0f, __builtin_amdgcn_rcpf(exp2_fast(a) + 1.0f), 1.0f);
}

__device__ __forceinline__ unsigned short f2bf_rne(float f) {
  unsigned u = __float_as_uint(f);
  u = u + 0x7fffu + ((u >> 16) & 1u);
  return (unsigned short)(u >> 16);
}

// pack two floats to bf16 pair (round-half-up): {lo16: bf(a), hi16: bf(b)}
__device__ __forceinline__ unsigned pack_bf16(float a, float b) {
  unsigned ua = __float_as_uint(a) + 0x8000u;
  unsigned ub = __float_as_uint(b) + 0x8000u;
  return __builtin_amdgcn_perm(ub, ua, 0x07060302u);
}

// ---------------- fused prep kernel ----------------
// hdr ints [0..7] = per-class cursors (memset to 0 before launch).
// packed23: bf16 [l(2)][c][k/8][j][k%8] — A-frags, value = PS*W[k][j]
#define PK2_BLKS 512   // transpose-pack W2/W3: block = (cl, k8), thread = j
#define MISC_BLKS 177
#define MISC_N 45184
#define SCAT_BLKS 512
#define PREP_GRID (PK2_BLKS + MISC_BLKS + SCAT_BLKS)

__global__ __launch_bounds__(256) void k_prep(
    const int* __restrict__ times,
    const float* __restrict__ W1, const float* __restrict__ b1,
    const float* __restrict__ W2, const float* __restrict__ b2,
    const float* __restrict__ W3, const float* __restrict__ b3,
    const float* __restrict__ W4, const float* __restrict__ b4,
    int* __restrict__ hdr, int* __restrict__ sortedIdx,
    unsigned short* __restrict__ packed23,
    float* __restrict__ w1p, float* __restrict__ b2p,
    float* __restrict__ b3p, float* __restrict__ b4p,
    unsigned short* __restrict__ W4p) {
  __shared__ int lh[NCLS], lbase[NCLS];

  int b = blockIdx.x;
  int tid = threadIdx.x;

  if (b < PK2_BLKS) {
    // LDS-free transpose-pack: thread (k8, j) reads 8 coalesced floats,
    // writes one 16B frag. cl = class-layer, 32 k8-blocks per cl.
    int cl = b >> 5;               // 0..15
    int k8 = b & 31;
    int j = tid;
    int l = cl >> 3, c = cl & 7;
    const float* W = (l ? W3 : W2) + c * 65536 + k8 * 8 * 256 + j;
    float v0 = W[0],        v1 = W[256],     v2 = W[2 * 256], v3 = W[3 * 256];
    float v4 = W[4 * 256],  v5 = W[5 * 256], v6 = W[6 * 256], v7 = W[7 * 256];
    uint4 pk;
    pk.x = (unsigned)f2bf_rne(PS * v0) | ((unsigned)f2bf_rne(PS * v1) << 16);
    pk.y = (unsigned)f2bf_rne(PS * v2) | ((unsigned)f2bf_rne(PS * v3) << 16);
    pk.z = (unsigned)f2bf_rne(PS * v4) | ((unsigned)f2bf_rne(PS * v5) << 16);
    pk.w = (unsigned)f2bf_rne(PS * v6) | ((unsigned)f2bf_rne(PS * v7) << 16);
    *(uint4*)&packed23[cl * 65536 + (k8 * 256 + j) * 8] = pk;
  } else if (b < PK2_BLKS + MISC_BLKS) {
    int e2 = (b - PK2_BLKS) * 256 + tid;
    if (e2 < 8192) {          // w1p: [c][j][4] = PS*{w0,w1,w2,b}
      int c = e2 >> 10, rem = e2 & 1023;
      int j = rem >> 2, t = rem & 3;
      float v = (t < 3) ? W1[c * 768 + t * 256 + j] : b1[c * 256 + j];
      w1p[e2] = PS * v;
    } else if (e2 < 10240) {
      int i = e2 - 8192;
      b2p[i] = PS * b2[i];
    } else if (e2 < 12288) {
      int i = e2 - 10240;
      b3p[i] = PS * b3[i];
    } else if (e2 < 12416) {  // b4p: [c][16]
      int i = e2 - 12288;
      int c = i >> 4, r = i & 15;
      b4p[i] = (r < 3) ? PS * b4[c * 3 + r] : 0.0f;
    } else if (e2 < MISC_N) { // W4p: [c][k/8][j(16)][k%8]
      int i = e2 - 12416;
      int c = i >> 12, rem = i & 4095;
      int jj = rem & 7, j = (rem >> 3) & 15, k = ((rem >> 7) << 3) + jj;
      float v = (j < 3) ? PS * W4[c * 768 + k * 3 + j] : 0.0f;
      W4p[c * 4096 + rem] = f2bf_rne(v);
    }
  } else {
    int sb = b - (PK2_BLKS + MISC_BLKS);
    if (tid < NCLS) lh[tid] = 0;
    __syncthreads();
    int i = sb * 256 + tid;
    int t = times[i];
    int r = atomicAdd(&lh[t], 1);
    __syncthreads();
    if (tid < NCLS) lbase[tid] = lh[tid] ? atomicAdd(&hdr[tid], lh[tid]) : 0;
    __syncthreads();
    sortedIdx[t * CAP + lbase[t] + r] = i;
  }
}

// ---------------- main MLP kernel ----------------
// 256 thr = 4 waves; wave w owns j in [w*64, w*64+64) (jf=0..3).
// Halved LDS B-read redundancy vs 8-wave split; 16 MFMA per 8 loads.
// Abuf (B-frags): [k/8][m][k%8]. A=weights (global/L2), B=acts (LDS)
// -> C[j][m]; lane holds 4 consecutive j at fixed m -> ds_write_b64 epilogue.
__device__ __forceinline__ void mfma_layer16(
    unsigned short (*__restrict__ Abuf)[MT][8],
    const bf16x8* __restrict__ Af,      // this layer's frag array (global)
    const float* __restrict__ biasp,    // [256] prescaled
    int tid) {
  int lane = tid & 63, w = tid >> 6;
  int quad = lane >> 4, l16 = lane & 15;
  int jbase = w * 64;

  f32x4 acc[4][4];  // [jf][mt]
#pragma unroll
  for (int jf = 0; jf < 4; jf++) {
    f32x4 bv = *(const f32x4*)&biasp[jbase + jf * 16 + quad * 4];
#pragma unroll
    for (int mt = 0; mt < 4; mt++) acc[jf][mt] = bv;
  }

#pragma unroll
  for (int kb = 0; kb < 8; kb++) {
    int kq = kb * 4 + quad;
    bf16x8 af[4], bfr[4];
#pragma unroll
    for (int jf = 0; jf < 4; jf++)
      af[jf] = Af[kq * 256 + jbase + jf * 16 + l16];
#pragma unroll
    for (int mt = 0; mt < 4; mt++)
      bfr[mt] = *(const bf16x8*)&Abuf[kq][mt * 16 + l16][0];
#pragma unroll
    for (int jf = 0; jf < 4; jf++)
#pragma unroll
      for (int mt = 0; mt < 4; mt++)
        acc[jf][mt] = __builtin_amdgcn_mfma_f32_16x16x32_bf16(af[jf], bfr[mt], acc[jf][mt], 0, 0, 0);
  }

  __syncthreads();  // all Abuf reads done block-wide; safe to overwrite

#pragma unroll
  for (int jf = 0; jf < 4; jf++) {
    int jbq = jbase + jf * 16 + quad * 4;  // 4 consecutive j per lane
#pragma unroll
    for (int mt = 0; mt < 4; mt++) {
      float t0 = tanh_p2(acc[jf][mt][0]);
      float t1 = tanh_p2(acc[jf][mt][1]);
      float t2 = tanh_p2(acc[jf][mt][2]);
      float t3 = tanh_p2(acc[jf][mt][3]);
      uint2 pk = make_uint2(pack_bf16(t0, t1), pack_bf16(t2, t3));
      *(uint2*)&Abuf[jbq >> 3][mt * 16 + l16][jbq & 7] = pk;
    }
  }
}

__global__ __launch_bounds__(256, 4) void k_mlp(
    const float* __restrict__ pos,
    const int* __restrict__ hdr, const int* __restrict__ sortedIdx,
    const unsigned short* __restrict__ packed23,
    const float* __restrict__ w1p, const float* __restrict__ b2p,
    const float* __restrict__ b3p, const float* __restrict__ b4p,
    const unsigned short* __restrict__ W4p,
    float* __restrict__ out) {

  __shared__ __align__(16) unsigned short Abuf[32][MT][8];  // 32 KB
  __shared__ __align__(16) float4 w1i[256];                 // 4 KB
  __shared__ __align__(16) float4 xpos4[MT];
  __shared__ int sIdx[MT];

  int b = blockIdx.x;
  int tid = threadIdx.x;

  // derive (class, tile) from per-class counts
  int c = -1, t0 = 0, cnt = 0;
  {
    int ts = 0;
#pragma unroll
    for (int cc = 0; cc < NCLS; cc++) {
      int cc_cnt = hdr[cc];
      int tiles = (cc_cnt + MT - 1) >> 6;
      if (b >= ts && b < ts + tiles) { c = cc; t0 = b - ts; cnt = cc_cnt; }
      ts += tiles;
    }
  }
  if (c < 0) return;
  int base = c * CAP + t0 * MT;
  int mCount = min(MT, cnt - t0 * MT);

  if (tid < MT) sIdx[tid] = sortedIdx[base + min(tid, mCount - 1)];
  w1i[tid] = ((const float4*)(w1p + (size_t)c * 1024))[tid];
  __syncthreads();
  if (tid < MT) {
    int idx = sIdx[tid] * 3;
    xpos4[tid] = make_float4(pos[idx], pos[idx + 1], pos[idx + 2], 0.0f);
  }
  __syncthreads();

  // ---- layer 1 (fp32 VALU): each wave covers 64 j ----
  {
    int m = tid & 63, q = tid >> 6;   // q in 0..3
    float4 xp = xpos4[m];
#pragma unroll
    for (int i8 = 0; i8 < 8; i8++) {
      int j8 = q * 8 + i8;
      unsigned pk[4];
#pragma unroll
      for (int jp = 0; jp < 4; jp++) {
        float t[2];
#pragma unroll
        for (int u = 0; u < 2; u++) {
          float4 wv = w1i[j8 * 8 + jp * 2 + u];
          float a = fmaf(xp.x, wv.x, fmaf(xp.y, wv.y, fmaf(xp.z, wv.z, wv.w)));
          t[u] = tanh_p2(a);
        }
        pk[jp] = pack_bf16(t[0], t[1]);
      }
      *(uint4*)&Abuf[j8][m][0] = make_uint4(pk[0], pk[1], pk[2], pk[3]);
    }
  }
  __syncthreads();

  // ---- layers 2,3 (MFMA, in-place Abuf) ----
  mfma_layer16(Abuf, (const bf16x8*)(packed23 + ((size_t)c << 16)),
               b2p + c * 256, tid);
  __syncthreads();
  mfma_layer16(Abuf, (const bf16x8*)(packed23 + ((size_t)(8 + c) << 16)),
               b3p + c * 256, tid);
  __syncthreads();

  // ---- layer 4 (16x16x32 MFMA, j padded 3->16): wave w -> m-tile w ----
  {
    int lane = tid & 63, w = tid >> 6;
    int quad = lane >> 4, l16 = lane & 15;
    f32x4 acc = *(const f32x4*)&b4p[c * 16 + quad * 4];
#pragma unroll
    for (int kb = 0; kb < 8; kb++) {
      int kq = kb * 4 + quad;
      bf16x8 a4 = *(const bf16x8*)&W4p[((size_t)c * 512 + kq * 16 + l16) * 8];
      bf16x8 b4f = *(const bf16x8*)&Abuf[kq][w * 16 + l16][0];
      acc = __builtin_amdgcn_mfma_f32_16x16x32_bf16(a4, b4f, acc, 0, 0, 0);
    }
    int m = w * 16 + l16;
    if (quad == 0 && m < mCount) {
      int o = sIdx[m] * 3;
      out[o + 0] = tanh_p2(acc[0]);
      out[o + 1] = tanh_p2(acc[1]);
      out[o + 2] = tanh_p2(acc[2]);
    }
  }
}

extern "C" void kernel_launch(void* const* d_in, const int* in_sizes, int n_in,
                              void* d_out, int out_size, void* d_ws, size_t ws_size,
                              hipStream_t stream) {
  const float* pos = (const float*)d_in[0];
  const int* times = (const int*)d_in[1];
  const float* W1 = (const float*)d_in[2];
  const float* b1 = (const float*)d_in[3];
  const float* W2 = (const float*)d_in[4];
  const float* b2 = (const float*)d_in[5];
  const float* W3 = (const float*)d_in[6];
  const float* b3 = (const float*)d_in[7];
  const float* W4 = (const float*)d_in[8];
  const float* b4 = (const float*)d_in[9];

  char* ws = (char*)d_ws;
  int* hdr = (int*)ws;
  int* sortedIdx = (int*)(ws + 4096);                    // 1 MB
  float* w1p = (float*)(ws + 1052672);                   // 32 KB
  float* b2p = (float*)(ws + 1085440);                   // 8 KB
  float* b3p = (float*)(ws + 1093632);                   // 8 KB
  float* b4p = (float*)(ws + 1101824);                   // 512 B
  unsigned short* W4p = (unsigned short*)(ws + 1102336); // 64 KB
  unsigned short* packed23 = (unsigned short*)(ws + (2u << 20)); // 2 MB
  float* out = (float*)d_out;

  hipMemsetAsync(d_ws, 0, 64, stream);
  k_prep<<<PREP_GRID, 256, 0, stream>>>(times, W1, b1, W2, b2, W3, b3, W4, b4,
                                        hdr, sortedIdx, packed23,
                                        w1p, b2p, b3p, b4p, W4p);
  k_mlp<<<N_PTS / MT + NCLS, 256, 0, stream>>>(
      pos, hdr, sortedIdx, packed23, w1p, b2p, b3p, b4p, W4p, out);
}